// Round 4
// baseline (102.824 us; speedup 1.0000x reference)
//
#include <hip/hip_runtime.h>
#include <hip/hip_bf16.h>

typedef __attribute__((ext_vector_type(4))) float f32x4;
typedef __attribute__((ext_vector_type(8))) short bf16x8;

#define HW     16384    // 128*128
#define CDIM   256
#define APITCH 80       // A row pitch bytes: 32k bf16 = 64B + 16B pad (16B-aligned, 2-way banks)
#define ABUF   10240    // 128 * 80
#define BOFF   20480    // B region start (2 A buffers)
#define BPITCH 528      // B row pitch bytes: 256k bf16 = 512B + 16B pad

__device__ __forceinline__ unsigned short f2bf(float x) {
    __hip_bfloat16 h = __float2bfloat16(x);
    return *reinterpret_cast<unsigned short*>(&h);
}
__device__ __forceinline__ float bf2f(unsigned short u) {
    union { unsigned u; float f; } c; c.u = ((unsigned)u) << 16;
    return c.f;
}

// F2t[px][c] = sum_k W1[c,k] * feat[k][px]  (bf16, channel-last)
// BM=128 px, BN=64 c (4 n-quarters), BK=32, 8 K-steps.
// W1-quarter staged bf16 in LDS once per block; A double-buffered in LDS with
// depth-2 register prefetch; ONE barrier per K-step. XCD swizzle: all 4
// n-siblings of an m-tile on one XCD -> feat re-reads hit that XCD's L2.
__global__ __launch_bounds__(256, 3) void f2_gemm(
    const float* __restrict__ feat, const float* __restrict__ W1,
    unsigned short* __restrict__ f2t) {
    __shared__ __attribute__((aligned(16))) char ldsc[BOFF + 64 * BPITCH]; // 54272 B

    const int t    = threadIdx.x;
    const int lane = t & 63;
    const int wid  = t >> 6;
    const int kg   = lane >> 4;      // 0..3
    const int rr   = lane & 15;

    // block -> (m-tile, n-quarter), bijective, n-siblings share an XCD
    const int b      = blockIdx.x;
    const int m      = ((b & 7) << 7) | (b >> 5);   // 0..1023
    const int nq     = (b >> 3) & 3;
    const int m_base = m << 7;
    const float* fb  = feat + (size_t)(m_base >> 14) * (CDIM * HW) + (m_base & (HW - 1));
    const float* wb  = W1 + (size_t)nq * 64 * CDIM;

    // A staging map: wave covers 8 k-rows; thread owns 4 consecutive k x 4 px
    const int pxq   = (lane & 31) << 2;                  // px quad base 0..124
    const int kloc0 = (wid << 3) + ((lane >> 5) << 2);   // 0..28, 4-aligned

    float av[2][4][4];      // [regbuf][dk][px-in-quad]
    f32x4 acc[4][2] = {};   // [mi(px)][ni(c)]

    auto load_a = [&](int kk, int buf) {
        const float* p = fb + (size_t)(kk * 32 + kloc0) * HW + pxq;
#pragma unroll
        for (int i = 0; i < 4; ++i) {
            const float4 v = *reinterpret_cast<const float4*>(p + (size_t)i * HW);
            av[buf][i][0] = v.x; av[buf][i][1] = v.y;
            av[buf][i][2] = v.z; av[buf][i][3] = v.w;
        }
    };
    auto write_a = [&](int buf, int lbuf) {
        char* base = ldsc + lbuf * ABUF;
#pragma unroll
        for (int p = 0; p < 4; ++p) {
            ushort4 w;
            w.x = f2bf(av[buf][0][p]); w.y = f2bf(av[buf][1][p]);
            w.z = f2bf(av[buf][2][p]); w.w = f2bf(av[buf][3][p]);
            *reinterpret_cast<ushort4*>(base + (pxq + p) * APITCH + kloc0 * 2) = w;
        }
    };

    // ---- prologue: A(0), A(1) in flight; stage W1-quarter (64c x 256k) ----
    load_a(0, 0);
    load_a(1, 1);
    {
        const int c  = t >> 2;           // 0..63
        const int k0 = (t & 3) << 6;     // 0,64,128,192
        const float* wp = wb + (size_t)c * CDIM + k0;
        char* brow = ldsc + BOFF + c * BPITCH;
#pragma unroll
        for (int j = 0; j < 8; ++j) {
            const float4 u = *reinterpret_cast<const float4*>(wp + j * 8);
            const float4 v = *reinterpret_cast<const float4*>(wp + j * 8 + 4);
            ushort4 lo, hi;
            lo.x = f2bf(u.x); lo.y = f2bf(u.y); lo.z = f2bf(u.z); lo.w = f2bf(u.w);
            hi.x = f2bf(v.x); hi.y = f2bf(v.y); hi.z = f2bf(v.z); hi.w = f2bf(v.w);
            *reinterpret_cast<ushort4*>(brow + ((k0 >> 3) + j) * 16)     = lo;
            *reinterpret_cast<ushort4*>(brow + ((k0 >> 3) + j) * 16 + 8) = hi;
        }
    }
    write_a(0, 0);
    __syncthreads();

    const int cfrag_base  = (wid >> 1) * 32;   // c slab within quarter
    const int pxfrag_base = (wid & 1) * 64;    // px slab

    // ---- main loop: one barrier per K-step, A(k+2) in flight during compute(k)
#pragma unroll
    for (int kk = 0; kk < 8; ++kk) {
        if (kk + 2 < 8) load_a(kk + 2, kk & 1);
        {
            bf16x8 wf[2], ff[4];
#pragma unroll
            for (int ni = 0; ni < 2; ++ni) {
                const int c = cfrag_base + ni * 16 + rr;
                wf[ni] = *reinterpret_cast<const bf16x8*>(
                    ldsc + BOFF + c * BPITCH + ((kk * 4 + kg) << 4));
            }
#pragma unroll
            for (int mi = 0; mi < 4; ++mi) {
                const int px = pxfrag_base + mi * 16 + rr;
                ff[mi] = *reinterpret_cast<const bf16x8*>(
                    ldsc + (kk & 1) * ABUF + px * APITCH + (kg << 4));
            }
#pragma unroll
            for (int mi = 0; mi < 4; ++mi)
#pragma unroll
                for (int ni = 0; ni < 2; ++ni)
                    acc[mi][ni] = __builtin_amdgcn_mfma_f32_16x16x32_bf16(
                        wf[ni], ff[mi], acc[mi][ni], 0, 0, 0);   // D[c][px]
        }
        if (kk + 1 < 8) {
            write_a((kk + 1) & 1, (kk + 1) & 1);
            __syncthreads();
        }
    }

    // ---- epilogue: lane holds 4 consecutive c for fixed px -> 8B stores ----
#pragma unroll
    for (int mi = 0; mi < 4; ++mi) {
        const int px = m_base + pxfrag_base + mi * 16 + rr;
#pragma unroll
        for (int ni = 0; ni < 2; ++ni) {
            const int c0 = nq * 64 + cfrag_base + ni * 16 + kg * 4;
            uint2 v;
            v.x = (unsigned)f2bf(acc[mi][ni][0]) | ((unsigned)f2bf(acc[mi][ni][1]) << 16);
            v.y = (unsigned)f2bf(acc[mi][ni][2]) | ((unsigned)f2bf(acc[mi][ni][3]) << 16);
            *reinterpret_cast<uint2*>(f2t + (size_t)px * CDIM + c0) = v;
        }
    }
}

// One wave per sample point: bilinear-weighted sum of 4 contiguous 512B rows
// of F2t, then relu(s+b1) . W2 -> 2 scalars, out = batch_edges + d.
__global__ __launch_bounds__(256) void point_kernel(
    const unsigned short* __restrict__ f2t,
    const float* __restrict__ be,
    const float* __restrict__ b1, const float* __restrict__ W2,
    float* __restrict__ out) {
    const int p    = (blockIdx.x * 256 + threadIdx.x) >> 6;   // 0..65535
    const int lane = threadIdx.x & 63;

    const float ex = be[p * 2 + 0];
    const float ey = be[p * 2 + 1];
    const float gx = ex * (2.0f / 128.0f) - 1.0f;
    const float gy = ey * (2.0f / 128.0f) - 1.0f;
    const float px = (gx + 1.0f) * 64.0f - 0.5f;
    const float py = (gy + 1.0f) * 64.0f - 0.5f;
    const float x0f = floorf(px), y0f = floorf(py);
    const int   x0 = (int)x0f, y0 = (int)y0f;
    const float wx1 = px - x0f, wy1 = py - y0f;
    const float wx0 = 1.0f - wx1, wy0 = 1.0f - wy1;

    const size_t pix_base = (size_t)(p >> 13) * HW;
    const int c0 = lane * 4;

    float s0 = 0.f, s1 = 0.f, s2 = 0.f, s3 = 0.f;
#pragma unroll
    for (int cy = 0; cy < 2; ++cy) {
        const int   yi  = y0 + cy;
        const float wy  = cy ? wy1 : wy0;
        const bool  yin = (yi >= 0) && (yi < 128);
        const int   yc  = min(max(yi, 0), 127);
#pragma unroll
        for (int cx = 0; cx < 2; ++cx) {
            const int   xi  = x0 + cx;
            const float wx  = cx ? wx1 : wx0;
            const bool  xin = (xi >= 0) && (xi < 128);
            const int   xc  = min(max(xi, 0), 127);
            const float w   = wx * wy * (float)(xin && yin);
            const ushort4 v = *reinterpret_cast<const ushort4*>(
                &f2t[(pix_base + (size_t)yc * 128 + xc) * 256 + c0]);
            s0 += w * bf2f(v.x); s1 += w * bf2f(v.y);
            s2 += w * bf2f(v.z); s3 += w * bf2f(v.w);
        }
    }
    const float4 bb  = *reinterpret_cast<const float4*>(&b1[c0]);
    const float4 w2a = *reinterpret_cast<const float4*>(&W2[c0]);
    const float4 w2b = *reinterpret_cast<const float4*>(&W2[256 + c0]);
    const float h0 = fmaxf(s0 + bb.x, 0.f);
    const float h1 = fmaxf(s1 + bb.y, 0.f);
    const float h2 = fmaxf(s2 + bb.z, 0.f);
    const float h3 = fmaxf(s3 + bb.w, 0.f);
    float a0 = h0 * w2a.x + h1 * w2a.y + h2 * w2a.z + h3 * w2a.w;
    float a1 = h0 * w2b.x + h1 * w2b.y + h2 * w2b.z + h3 * w2b.w;
#pragma unroll
    for (int off = 32; off > 0; off >>= 1) {
        a0 += __shfl_xor(a0, off);
        a1 += __shfl_xor(a1, off);
    }
    if (lane == 0) {
        out[p * 2 + 0] = ex + a0;
        out[p * 2 + 1] = ey + a1;
    }
}

extern "C" void kernel_launch(void* const* d_in, const int* in_sizes, int n_in,
                              void* d_out, int out_size, void* d_ws, size_t ws_size,
                              hipStream_t stream) {
    const float* feat = (const float*)d_in[0];
    const float* be   = (const float*)d_in[1];
    const float* W1   = (const float*)d_in[2];
    const float* b1   = (const float*)d_in[3];
    const float* W2   = (const float*)d_in[4];
    float* out = (float*)d_out;
    unsigned short* f2t = (unsigned short*)d_ws;   // 131072*256 bf16 = 64 MiB

    f2_gemm<<<4096, 256, 0, stream>>>(feat, W1, f2t);
    point_kernel<<<16384, 256, 0, stream>>>(f2t, be, b1, W2, out);
}